// Round 1
// baseline (2379.114 us; speedup 1.0000x reference)
//
#include <hip/hip_runtime.h>
#include <hip/hip_bf16.h>
#include <math.h>

#define DEVFN static __device__ __forceinline__

typedef __attribute__((ext_vector_type(8))) short short8;
typedef __attribute__((ext_vector_type(4))) float floatx4;

DEVFN float bf2f(__hip_bfloat16 h){ return __bfloat162float(h); }
DEVFN __hip_bfloat16 f2bf(float f){ return __float2bfloat16(f); }
DEVFN float toF(float f){ return f; }
DEVFN float toF(__hip_bfloat16 h){ return __bfloat162float(h); }
DEVFN void storeC(float* p, float v){ *p = v; }
DEVFN void storeC(__hip_bfloat16* p, float v){ *p = f2bf(v); }

DEVFN void gld_lds16(const __hip_bfloat16* g, unsigned short* l){
  __builtin_amdgcn_global_load_lds((const __attribute__((address_space(1))) void*)g,
                                   (__attribute__((address_space(3))) void*)l, 16, 0, 0);
}

// ---------------------------------------------------------------------------
// C = alpha * A(MxK,bf16) * B(NxK,bf16)^T   fp32 accumulate
// EPI: 0 none, 1 multiply row-bias, 2 add row-bias. bias[(row>>10)*biasLd+col]
// grid: x = N/128, y = M/128, z batches: z1=z/Z2, z2=z%Z2 with per-axis strides
// ---------------------------------------------------------------------------
template<typename OUT, int EPI>
__global__ __launch_bounds__(256)
void gemm_bt(const __hip_bfloat16* __restrict__ A, const __hip_bfloat16* __restrict__ B,
             OUT* __restrict__ C, const float* __restrict__ bias,
             int K, int ldc, int Nstore, int biasLd, float alpha,
             int Z2, long sA1, long sA2, long sB1, long sB2, long sC1, long sC2)
{
  __shared__ unsigned short As[128*32];
  __shared__ unsigned short Bs[128*32];
  const int t = threadIdx.x;
  const int z  = blockIdx.z;
  const int z1 = z / Z2, z2 = z - z1*Z2;
  A += (long)z1*sA1 + (long)z2*sA2;
  B += (long)z1*sB1 + (long)z2*sB2;
  C += (long)z1*sC1 + (long)z2*sC2;

  const int lane = t & 63, wv = t >> 6;
  const int waveM = wv >> 1, waveN = wv & 1;
  const int quad = lane >> 4, lrow = lane & 15;

  const __hip_bfloat16* Ab = A + (long)blockIdx.y*128*K;
  const __hip_bfloat16* Bb = B + (long)blockIdx.x*128*K;

  const int c1 = t + 256;
  // chunk c (16B = 8 bf16): row = c>>2, k-offset = (c&3)*8  -> LDS byte off c*16
  const __hip_bfloat16* ga0 = Ab + (long)(t >>2)*K + (t &3)*8;
  const __hip_bfloat16* ga1 = Ab + (long)(c1>>2)*K + (c1&3)*8;
  const __hip_bfloat16* gb0 = Bb + (long)(t >>2)*K + (t &3)*8;
  const __hip_bfloat16* gb1 = Bb + (long)(c1>>2)*K + (c1&3)*8;
  unsigned short* la0 = As + t*8;
  unsigned short* la1 = As + c1*8;
  unsigned short* lb0 = Bs + t*8;
  unsigned short* lb1 = Bs + c1*8;

  floatx4 acc[4][4] = {};

  for (int kb = 0; kb < K; kb += 32) {
    gld_lds16(ga0 + kb, la0);
    gld_lds16(ga1 + kb, la1);
    gld_lds16(gb0 + kb, lb0);
    gld_lds16(gb1 + kb, lb1);
    __syncthreads();
    const short8* As8 = (const short8*)As;
    const short8* Bs8 = (const short8*)Bs;
    short8 af[4], bfr[4];
#pragma unroll
    for (int i = 0; i < 4; i++) af[i]  = As8[(waveM*64 + i*16 + lrow)*4 + quad];
#pragma unroll
    for (int i = 0; i < 4; i++) bfr[i] = Bs8[(waveN*64 + i*16 + lrow)*4 + quad];
#pragma unroll
    for (int mi = 0; mi < 4; mi++)
#pragma unroll
      for (int ni = 0; ni < 4; ni++)
        acc[mi][ni] = __builtin_amdgcn_mfma_f32_16x16x32_bf16(af[mi], bfr[ni], acc[mi][ni], 0, 0, 0);
    __syncthreads();
  }

  const int colBase = blockIdx.x*128 + waveN*64 + lrow;
  const int rowBase = blockIdx.y*128 + waveM*64 + quad*4;
#pragma unroll
  for (int ni = 0; ni < 4; ni++) {
    int col = colBase + ni*16;
    if (col >= Nstore) continue;
#pragma unroll
    for (int mi = 0; mi < 4; mi++) {
      int row0 = rowBase + mi*16;
#pragma unroll
      for (int r = 0; r < 4; r++) {
        int row = row0 + r;
        float vv = acc[mi][ni][r] * alpha;
        if (EPI == 1) vv *= bias[(row >> 10)*biasLd + col];
        if (EPI == 2) vv += bias[(row >> 10)*biasLd + col];
        storeC(&C[(long)row*ldc + col], vv);
      }
    }
  }
}

// ---------------------------------------------------------------------------
// small kernels
// ---------------------------------------------------------------------------
__global__ void colsum_kernel(const float* __restrict__ We, float* __restrict__ colsum){
  int j = threadIdx.x;                      // 768 threads
  float acc = 0.f;
  for (int r = blockIdx.x; r < 50257; r += gridDim.x) acc += We[(long)r*768 + j];
  atomicAdd(&colsum[j], acc);
}

__global__ void cvt_pad_we(const float* __restrict__ W, __hip_bfloat16* __restrict__ out){
  int c = blockIdx.x*256 + threadIdx.x;     // 0..767
  int r = blockIdx.y;                       // 0..50303
  float v = (r < 50257) ? W[(long)r*768 + c] : 0.f;
  out[(long)r*768 + c] = f2bf(v);
}

__global__ void cvt_bf16(const float* __restrict__ in, __hip_bfloat16* __restrict__ out, int n){
  int i = blockIdx.x*256 + threadIdx.x;
  if (i < n) out[i] = f2bf(in[i]);
}

__global__ void embed_v(const float* __restrict__ We, const int* __restrict__ x,
                        const float* __restrict__ colsum, __hip_bfloat16* __restrict__ v, float invV){
  int c  = blockIdx.x*256 + threadIdx.x;    // 0..767
  int bs = blockIdx.y;                      // 0..4095
  int tok = x[bs];
  v[(long)bs*768 + c] = f2bf(We[(long)tok*768 + c] - colsum[c]*invV);
}

template<typename TIN>
__global__ void transpose_cvt(const TIN* __restrict__ in, __hip_bfloat16* __restrict__ out,
                              int ldi, int ldo, long inZ, long outZ){
  __shared__ float tile[32][33];
  in  += (long)blockIdx.z*inZ;
  out += (long)blockIdx.z*outZ;
  int c0 = blockIdx.x*32, r0 = blockIdx.y*32;
  int tx = threadIdx.x, ty = threadIdx.y;
#pragma unroll
  for (int i = 0; i < 4; i++) tile[ty + i*8][tx] = toF(in[(long)(r0 + ty + i*8)*ldi + c0 + tx]);
  __syncthreads();
#pragma unroll
  for (int i = 0; i < 4; i++) out[(long)(c0 + ty + i*8)*ldo + r0 + tx] = f2bf(tile[tx][ty + i*8]);
}

__global__ __launch_bounds__(256)
void db_kernel(const float* __restrict__ We, const int* __restrict__ x,
               const float* __restrict__ colsum, const float* __restrict__ Blr,
               float* __restrict__ dB, float invV){
  int i = blockIdx.x*256 + threadIdx.x;     // < 3072
  int b = i / 768, e = i - b*768;
  const int* xb = x + b*1024;
  float acc = 0.f;
  for (int s = 0; s < 1024; ++s) acc += We[(long)xb[s]*768 + e];
  dB[i] = (acc - 1024.f*colsum[e]*invV) * Blr[0];
}

__global__ __launch_bounds__(256)
void softmax_scale(const float* __restrict__ S, __hip_bfloat16* __restrict__ attn,
                   const float* __restrict__ Alr){
  const int row = blockIdx.x;               // h*1024 + q
  const int h = row >> 10;
  const int t = threadIdx.x;
  const float4* S4 = (const float4*)(S + (long)row*1024);
  float4 xv = S4[t];
  float m = fmaxf(fmaxf(xv.x, xv.y), fmaxf(xv.z, xv.w));
#pragma unroll
  for (int o = 32; o; o >>= 1) m = fmaxf(m, __shfl_xor(m, o));
  __shared__ float rmax[4], rsum[4];
  if ((t & 63) == 0) rmax[t >> 6] = m;
  __syncthreads();
  m = fmaxf(fmaxf(rmax[0], rmax[1]), fmaxf(rmax[2], rmax[3]));
  float e0 = expf(xv.x - m), e1 = expf(xv.y - m), e2 = expf(xv.z - m), e3 = expf(xv.w - m);
  float s = e0 + e1 + e2 + e3;
#pragma unroll
  for (int o = 32; o; o >>= 1) s += __shfl_xor(s, o);
  if ((t & 63) == 0) rsum[t >> 6] = s;
  __syncthreads();
  s = rsum[0] + rsum[1] + rsum[2] + rsum[3];
  float sc = Alr[h] / s;
  __hip_bfloat16* ap = attn + (long)row*1024 + t*4;
  ap[0] = f2bf(e0*sc); ap[1] = f2bf(e1*sc); ap[2] = f2bf(e2*sc); ap[3] = f2bf(e3*sc);
}

// main (rank-1, fp32-exact) path: g = dB/1024 ; m1 = g @ ff_w1^T ; store gelu, gelu'
__global__ __launch_bounds__(256)
void main_ff1(const float* __restrict__ dB, const float* __restrict__ ffw1,
              float* __restrict__ G0, float* __restrict__ G1){
  int o = blockIdx.x;                       // < 12288
  int b = o / 3072, n = o - b*3072;
  const float* w = ffw1 + (long)n*768;
  const float* g = dB + b*768;
  float acc = 0.f;
  for (int e = threadIdx.x; e < 768; e += 256) acc += g[e]*w[e];
#pragma unroll
  for (int o2 = 32; o2; o2 >>= 1) acc += __shfl_xor(acc, o2);
  __shared__ float red[4];
  if ((threadIdx.x & 63) == 0) red[threadIdx.x >> 6] = acc;
  __syncthreads();
  if (threadIdx.x == 0){
    float m  = (red[0] + red[1] + red[2] + red[3]) * (1.0f/1024.0f);
    float ph = 0.5f*(1.0f + erff(m*0.70710678118654752f));
    G0[o] = m*ph;                                             // gelu(m)
    G1[o] = ph + m*0.39894228040143268f*expf(-0.5f*m*m);      // gelu'(m)
  }
}

__global__ __launch_bounds__(256)
void main_ff2(const float* __restrict__ G0, const float* __restrict__ ffw2, float* __restrict__ f2m){
  int o = blockIdx.x;                       // < 3072
  int b = o / 768, e = o - b*768;
  const float* w = ffw2 + (long)e*3072;
  const float* g = G0 + b*3072;
  float acc = 0.f;
  for (int n = threadIdx.x; n < 3072; n += 256) acc += g[n]*w[n];
#pragma unroll
  for (int o2 = 32; o2; o2 >>= 1) acc += __shfl_xor(acc, o2);
  __shared__ float red[4];
  if ((threadIdx.x & 63) == 0) red[threadIdx.x >> 6] = acc;
  __syncthreads();
  if (threadIdx.x == 0) f2m[o] = red[0] + red[1] + red[2] + red[3];
}

__global__ __launch_bounds__(256)
void main_logits_k(const float* __restrict__ We, const float* __restrict__ f2m,
                   float* __restrict__ Lmain){
  int vc = blockIdx.x;                      // < 50257
  int t = threadIdx.x;
  const float* w = We + (long)vc*768;
  float a[4] = {0.f, 0.f, 0.f, 0.f};
  for (int e = t; e < 768; e += 256){
    float wv = w[e];
    a[0] += wv*f2m[e]; a[1] += wv*f2m[768 + e]; a[2] += wv*f2m[1536 + e]; a[3] += wv*f2m[2304 + e];
  }
#pragma unroll
  for (int j = 0; j < 4; j++)
#pragma unroll
    for (int o = 32; o; o >>= 1) a[j] += __shfl_xor(a[j], o);
  __shared__ float red[4][4];
  if ((t & 63) == 0){ int w2 = t >> 6; red[w2][0] = a[0]; red[w2][1] = a[1]; red[w2][2] = a[2]; red[w2][3] = a[3]; }
  __syncthreads();
  if (t < 4) Lmain[t*50304 + vc] = red[0][t] + red[1][t] + red[2][t] + red[3][t];
}

// ---------------------------------------------------------------------------
extern "C" void kernel_launch(void* const* d_in, const int* in_sizes, int n_in,
                              void* d_out, int out_size, void* d_ws, size_t ws_size,
                              hipStream_t stream)
{
  const int*   x    = (const int*)  d_in[0];
  const float* We   = (const float*)d_in[1];
  const float* Wp   = (const float*)d_in[2];
  const float* Wq   = (const float*)d_in[3];
  const float* Wk   = (const float*)d_in[4];
  const float* Wv   = (const float*)d_in[5];
  const float* Alr  = (const float*)d_in[6];
  const float* Blr  = (const float*)d_in[7];
  const float* ffw1 = (const float*)d_in[8];
  const float* ffw2 = (const float*)d_in[9];
  float* out = (float*)d_out;

  const float invV = 1.0f/50257.0f;

  // ---- ws layout (must survive into the final logits GEMM): ~84.5 MB
  char* ws = (char*)d_ws;
  size_t wo = 0;
  auto wsa = [&](size_t bytes){ void* p = ws + wo; wo += (bytes + 255) & ~(size_t)255; return p; };
  __hip_bfloat16* We_bf  = (__hip_bfloat16*)wsa((size_t)50304*768*2);   // padded V rows
  __hip_bfloat16* f2d    = (__hip_bfloat16*)wsa((size_t)4096*768*2);    // delta-path ff2 out
  float*          Lmain  = (float*)wsa((size_t)4*50304*4);              // rank-1 logits bias
  float*          colsum = (float*)wsa(768*4);
  float*          dB     = (float*)wsa(3072*4);
  float*          G0     = (float*)wsa(12288*4);
  float*          G1     = (float*)wsa(12288*4);
  float*          f2m    = (float*)wsa(3072*4);

  // ---- scratch inside d_out (dead before final logits GEMM overwrites it): ~286 MB
  char* ob = (char*)d_out;
  size_t oo = 0;
  auto oba = [&](size_t bytes){ void* p = ob + oo; oo += (bytes + 255) & ~(size_t)255; return p; };
  __hip_bfloat16* p_bf    = (__hip_bfloat16*)oba((size_t)1024*768*2);
  __hip_bfloat16* WqT     = (__hip_bfloat16*)oba((size_t)12*768*768*2);
  __hip_bfloat16* WkT     = (__hip_bfloat16*)oba((size_t)12*768*768*2);
  __hip_bfloat16* WvT     = (__hip_bfloat16*)oba((size_t)768*9216*2);
  __hip_bfloat16* v_bf    = (__hip_bfloat16*)oba((size_t)4096*768*2);
  __hip_bfloat16* vT      = (__hip_bfloat16*)oba((size_t)4096*768*2);
  __hip_bfloat16* ffw1_bf = (__hip_bfloat16*)oba((size_t)3072*768*2);
  __hip_bfloat16* ffw2_bf = (__hip_bfloat16*)oba((size_t)768*3072*2);
  __hip_bfloat16* Qb      = (__hip_bfloat16*)oba((size_t)12*1024*768*2);
  __hip_bfloat16* Kb      = (__hip_bfloat16*)oba((size_t)12*1024*768*2);
  float*          scoresF = (float*)oba((size_t)12*1024*1024*4);
  __hip_bfloat16* attn    = (__hip_bfloat16*)oba((size_t)12*1024*1024*2);
  __hip_bfloat16* AVr     = (__hip_bfloat16*)oba((size_t)4096*9216*2);
  __hip_bfloat16* f_d     = (__hip_bfloat16*)oba((size_t)4096*768*2);
  __hip_bfloat16* h1d     = (__hip_bfloat16*)oba((size_t)4096*3072*2);

  // ---- constant-path reductions
  hipMemsetAsync(colsum, 0, 768*4, stream);
  colsum_kernel<<<256, 768, 0, stream>>>(We, colsum);
  cvt_pad_we<<<dim3(3, 50304), 256, 0, stream>>>(We, We_bf);
  embed_v<<<dim3(3, 4096), 256, 0, stream>>>(We, x, colsum, v_bf, invV);
  transpose_cvt<__hip_bfloat16><<<dim3(24, 32, 4), dim3(32, 8), 0, stream>>>(v_bf, vT, 768, 1024, 786432, 786432);
  db_kernel<<<12, 256, 0, stream>>>(We, x, colsum, Blr, dB, invV);

  // ---- fp32-exact rank-1 main path (delta_B through FFN to logits bias)
  main_ff1<<<12288, 256, 0, stream>>>(dB, ffw1, G0, G1);
  main_ff2<<<3072, 256, 0, stream>>>(G0, ffw2, f2m);
  main_logits_k<<<50257, 256, 0, stream>>>(We, f2m, Lmain);

  // ---- weight prep for delta path
  transpose_cvt<float><<<dim3(24, 24, 12), dim3(32, 8), 0, stream>>>(Wq, WqT, 768, 768, 589824, 589824);
  transpose_cvt<float><<<dim3(24, 24, 12), dim3(32, 8), 0, stream>>>(Wk, WkT, 768, 768, 589824, 589824);
  transpose_cvt<float><<<dim3(24, 24, 12), dim3(32, 8), 0, stream>>>(Wv, WvT, 768, 9216, 589824, 768);
  cvt_bf16<<<3072, 256, 0, stream>>>(Wp, p_bf, 786432);
  cvt_bf16<<<9216, 256, 0, stream>>>(ffw1, ffw1_bf, 2359296);
  cvt_bf16<<<9216, 256, 0, stream>>>(ffw2, ffw2_bf, 2359296);

  // ---- attention (delta_A) path, bf16 MFMA GEMMs
  // Q[h] = p @ WqT[h]^T   (M=1024,N=768,K=768), z = h
  gemm_bt<__hip_bfloat16,0><<<dim3(6, 8, 12), 256, 0, stream>>>(
      p_bf, WqT, Qb, nullptr, 768, 768, 768, 0, 1.f, 1, 0,0, 589824,0, 786432,0);
  gemm_bt<__hip_bfloat16,0><<<dim3(6, 8, 12), 256, 0, stream>>>(
      p_bf, WkT, Kb, nullptr, 768, 768, 768, 0, 1.f, 1, 0,0, 589824,0, 786432,0);
  // scores[h] = Q[h] @ K[h]^T / sqrt(768)
  gemm_bt<float,0><<<dim3(8, 8, 12), 256, 0, stream>>>(
      Qb, Kb, scoresF, nullptr, 768, 1024, 1024, 0, 0.036084391824351615f, 1,
      786432,0, 786432,0, 1048576,0);
  softmax_scale<<<12288, 256, 0, stream>>>(scoresF, attn, Alr);  // attn *= A_lr[h]
  // AV[b,h] = attn[h] @ v[b] : A=attn[h](1024x1024), B=vT[b](768x1024) ; C row b, col block h
  gemm_bt<__hip_bfloat16,0><<<dim3(6, 8, 48), 256, 0, stream>>>(
      attn, vT, AVr, nullptr, 1024, 9216, 768, 0, 1.f, 4,
      1048576,0, 0,786432, 768,9437184);
  // f_delta = (1/1024) * AVr(4096x9216) @ WvT(768x9216)^T
  gemm_bt<__hip_bfloat16,0><<<dim3(6, 32, 1), 256, 0, stream>>>(
      AVr, WvT, f_d, nullptr, 9216, 768, 768, 0, 1.f/1024.f, 1, 0,0,0,0,0,0);
  // h1_delta = gelu'(m1) * (f_delta @ ff_w1^T)
  gemm_bt<__hip_bfloat16,1><<<dim3(24, 32, 1), 256, 0, stream>>>(
      f_d, ffw1_bf, h1d, G1, 768, 3072, 3072, 3072, 1.f, 1, 0,0,0,0,0,0);
  // f2_delta = h1_delta @ ff_w2^T  (lands in ws — read during final GEMM)
  gemm_bt<__hip_bfloat16,0><<<dim3(6, 32, 1), 256, 0, stream>>>(
      h1d, ffw2_bf, f2d, nullptr, 3072, 768, 768, 0, 1.f, 1, 0,0,0,0,0,0);
  // logits = f2_delta @ We^T + Lmain[b]   (overwrites all of d_out)
  gemm_bt<float,2><<<dim3(393, 32, 1), 256, 0, stream>>>(
      f2d, We_bf, out, Lmain, 768, 50257, 50257, 50304, 1.f, 1, 0,0,0,0,0,0);

  (void)in_sizes; (void)n_in; (void)out_size; (void)ws_size;
}